// Round 1
// baseline (11714.368 us; speedup 1.0000x reference)
//
#include <hip/hip_runtime.h>
#include <math.h>

#define N   200000
#define E   6400000
#define IN_ 128
#define D   16
#define G   1024
#define BNEPS 1e-5f

// ---------- helpers ----------
__device__ __forceinline__ unsigned f2ord(float f) {
    unsigned b = __float_as_uint(f);
    return (b & 0x80000000u) ? ~b : (b | 0x80000000u);
}
__device__ __forceinline__ float ord2f(unsigned u) {
    return __uint_as_float((u & 0x80000000u) ? (u & 0x7FFFFFFFu) : ~u);
}

// ---------- degree count (in-degree by col) ----------
__global__ __launch_bounds__(256) void k_deg(const int* __restrict__ col,
                                             unsigned* __restrict__ degi) {
    int e = blockIdx.x * 256 + threadIdx.x;
    if (e < E) atomicAdd(&degi[col[e]], 1u);
}

__global__ __launch_bounds__(256) void k_dis(const unsigned* __restrict__ degi,
                                             float* __restrict__ dis) {
    int i = blockIdx.x * 256 + threadIdx.x;
    if (i < N) dis[i] = rsqrtf((float)degi[i] + 1.0f);
}

// ---------- h1 = x @ W1  (N x 128 @ 128 x 16) ----------
__global__ __launch_bounds__(256) void k_gemm1(const float* __restrict__ x,
                                               const float* __restrict__ W1,
                                               float* __restrict__ h) {
    __shared__ float Wls[IN_ * D];    // 8 KB
    __shared__ float xs[16 * 129];    // 16 rows, padded stride 129
    int tid = threadIdx.x;
    for (int i = tid; i < IN_ * D; i += 256) Wls[i] = W1[i];
    int g = tid >> 4, j = tid & 15;
    const int ntiles = N / 16;  // 12500, exact
    for (int t = blockIdx.x; t < ntiles; t += gridDim.x) {
        __syncthreads();  // protects xs reuse; also covers first-iter Wls
        int n0 = t * 16;
        // 16 rows are contiguous: load 2048 consecutive floats, coalesced
        for (int i = tid; i < 16 * IN_; i += 256) {
            xs[(i >> 7) * 129 + (i & 127)] = x[(size_t)n0 * IN_ + i];
        }
        __syncthreads();
        float acc = 0.f;
#pragma unroll
        for (int k = 0; k < IN_; k++) acc += xs[g * 129 + k] * Wls[k * D + j];
        h[(size_t)(n0 + g) * D + j] = acc;
    }
}

// ---------- edge aggregation: agg[col] += h[row] * dis[row]*dis[col] ----------
__global__ __launch_bounds__(256) void k_edge(const int* __restrict__ row,
                                              const int* __restrict__ col,
                                              const float* __restrict__ dis,
                                              const float* __restrict__ h,
                                              float* __restrict__ agg) {
    int e = blockIdx.x * 256 + threadIdx.x;
    if (e >= E) return;
    int r = row[e], c = col[e];
    float coef = dis[r] * dis[c];
    const float4* hp = (const float4*)(h + (size_t)r * D);
    float4 a = hp[0], b = hp[1], cc = hp[2], d = hp[3];
    float* ap = agg + (size_t)c * D;
    atomicAdd(ap + 0,  a.x  * coef);
    atomicAdd(ap + 1,  a.y  * coef);
    atomicAdd(ap + 2,  a.z  * coef);
    atomicAdd(ap + 3,  a.w  * coef);
    atomicAdd(ap + 4,  b.x  * coef);
    atomicAdd(ap + 5,  b.y  * coef);
    atomicAdd(ap + 6,  b.z  * coef);
    atomicAdd(ap + 7,  b.w  * coef);
    atomicAdd(ap + 8,  cc.x * coef);
    atomicAdd(ap + 9,  cc.y * coef);
    atomicAdd(ap + 10, cc.z * coef);
    atomicAdd(ap + 11, cc.w * coef);
    atomicAdd(ap + 12, d.x  * coef);
    atomicAdd(ap + 13, d.y  * coef);
    atomicAdd(ap + 14, d.z  * coef);
    atomicAdd(ap + 15, d.w  * coef);
}

// ---------- x1 = BN(ReLU(agg + h*dis^2 + b1)); h <- x1 @ W2 ----------
__global__ __launch_bounds__(256) void k_combine1(float* __restrict__ h,  // in h1 / out h2
                                                  const float* __restrict__ agg,
                                                  const float* __restrict__ dis,
                                                  const float* __restrict__ b1,
                                                  const float* __restrict__ g1,
                                                  const float* __restrict__ be1,
                                                  const float* __restrict__ m1,
                                                  const float* __restrict__ v1,
                                                  const float* __restrict__ W2) {
    __shared__ float W2s[D * D];
    __shared__ float scale[D], shift[D], bs[D];
    int tid = threadIdx.x;
    if (tid < D * D) W2s[tid] = W2[tid];
    if (tid < D) {
        float sc = g1[tid] * rsqrtf(v1[tid] + BNEPS);
        scale[tid] = sc;
        shift[tid] = be1[tid] - m1[tid] * sc;
        bs[tid] = b1[tid];
    }
    __syncthreads();
    int i = blockIdx.x * 256 + tid;
    if (i >= N) return;
    float di = dis[i];
    float d2 = di * di;
    float x1v[D];
    const float* hp = h + (size_t)i * D;
    const float* ap = agg + (size_t)i * D;
#pragma unroll
    for (int j = 0; j < D; j++) {
        float t = ap[j] + hp[j] * d2 + bs[j];
        t = fmaxf(t, 0.f);
        x1v[j] = t * scale[j] + shift[j];
    }
    float o[D];
#pragma unroll
    for (int j = 0; j < D; j++) {
        float acc = 0.f;
#pragma unroll
        for (int k = 0; k < D; k++) acc += x1v[k] * W2s[k * D + j];
        o[j] = acc;
    }
    float4* op = (float4*)(h + (size_t)i * D);
    op[0] = make_float4(o[0], o[1], o[2], o[3]);
    op[1] = make_float4(o[4], o[5], o[6], o[7]);
    op[2] = make_float4(o[8], o[9], o[10], o[11]);
    op[3] = make_float4(o[12], o[13], o[14], o[15]);
}

// ---------- x2 = BN(ReLU(agg2 + h2*dis^2 + b2)); pool into per-graph max/sum ----------
__global__ __launch_bounds__(256) void k_combine2(const float* __restrict__ h,
                                                  const float* __restrict__ agg,
                                                  const float* __restrict__ dis,
                                                  const int* __restrict__ batch,
                                                  const float* __restrict__ b2,
                                                  const float* __restrict__ g2,
                                                  const float* __restrict__ be2,
                                                  const float* __restrict__ m2,
                                                  const float* __restrict__ v2,
                                                  unsigned* __restrict__ gmaxT,
                                                  float* __restrict__ gsum,
                                                  unsigned* __restrict__ gcnt) {
    __shared__ float scale[D], shift[D], bs[D];
    int tid = threadIdx.x;
    if (tid < D) {
        float sc = g2[tid] * rsqrtf(v2[tid] + BNEPS);
        scale[tid] = sc;
        shift[tid] = be2[tid] - m2[tid] * sc;
        bs[tid] = b2[tid];
    }
    __syncthreads();
    int i = blockIdx.x * 256 + tid;
    if (i >= N) return;
    float di = dis[i];
    float d2 = di * di;
    const float* hp = h + (size_t)i * D;
    const float* ap = agg + (size_t)i * D;
    int gid = batch[i];
    atomicAdd(&gcnt[gid], 1u);
    unsigned* gmp = gmaxT + (size_t)gid * D;
    float* gsp = gsum + (size_t)gid * D;
#pragma unroll
    for (int j = 0; j < D; j++) {
        float t = ap[j] + hp[j] * d2 + bs[j];
        t = fmaxf(t, 0.f);
        float x2 = t * scale[j] + shift[j];
        atomicMax(gmp + j, f2ord(x2));
        atomicAdd(gsp + j, x2);
    }
}

// ---------- head: emb = ReLU([gmax,gmean] @ Wb + bb); out = sigmoid(emb @ Wm + bm) ----------
__global__ __launch_bounds__(256) void k_head(const unsigned* __restrict__ gmaxT,
                                              const float* __restrict__ gsum,
                                              const unsigned* __restrict__ gcnt,
                                              const float* __restrict__ Wb,
                                              const float* __restrict__ bb,
                                              const float* __restrict__ Wm,
                                              const float* __restrict__ bm,
                                              float* __restrict__ out) {
    __shared__ float Wbs[32 * 16];
    __shared__ float bbs[16], Wms[16];
    __shared__ float bm0;
    int tid = threadIdx.x;
    for (int i = tid; i < 32 * 16; i += 256) Wbs[i] = Wb[i];
    if (tid < 16) { bbs[tid] = bb[tid]; Wms[tid] = Wm[tid]; }
    if (tid == 0) bm0 = bm[0];
    __syncthreads();
    int g = blockIdx.x * 256 + tid;
    if (g >= G) return;
    float in[32];
    float inv = 1.0f / (float)gcnt[g];
#pragma unroll
    for (int j = 0; j < D; j++) {
        in[j] = ord2f(gmaxT[(size_t)g * D + j]);
        in[16 + j] = gsum[(size_t)g * D + j] * inv;
    }
    float z = bm0;
#pragma unroll
    for (int j = 0; j < 16; j++) {
        float acc = bbs[j];
#pragma unroll
        for (int k = 0; k < 32; k++) acc += in[k] * Wbs[k * 16 + j];
        acc = fmaxf(acc, 0.f);
        z += acc * Wms[j];
    }
    out[g] = 1.0f / (1.0f + expf(-z));
}

extern "C" void kernel_launch(void* const* d_in, const int* in_sizes, int n_in,
                              void* d_out, int out_size, void* d_ws, size_t ws_size,
                              hipStream_t stream) {
    const float* x   = (const float*)d_in[0];
    const int* ei    = (const int*)d_in[1];
    const int* rowp  = ei;
    const int* colp  = ei + E;
    const int* batch = (const int*)d_in[2];
    const float* W1  = (const float*)d_in[3];
    const float* b1  = (const float*)d_in[4];
    const float* g1  = (const float*)d_in[5];
    const float* be1 = (const float*)d_in[6];
    const float* m1  = (const float*)d_in[7];
    const float* v1  = (const float*)d_in[8];
    const float* W2  = (const float*)d_in[9];
    const float* b2  = (const float*)d_in[10];
    const float* g2  = (const float*)d_in[11];
    const float* be2 = (const float*)d_in[12];
    const float* m2  = (const float*)d_in[13];
    const float* v2  = (const float*)d_in[14];
    const float* Wb  = (const float*)d_in[15];
    const float* bb  = (const float*)d_in[16];
    const float* Wm  = (const float*)d_in[17];
    const float* bm  = (const float*)d_in[18];
    float* out = (float*)d_out;

    char* ws = (char*)d_ws;
    // layout (bytes): dis[0, 800000) h[800000, 13600000) agg[13600000, 26400000)
    //                 gmaxT[26400000,+64K) gsum[+64K) gcnt[+4K)
    float*    dis   = (float*)(ws);
    float*    h     = (float*)(ws + 800000);
    float*    agg   = (float*)(ws + 13600000);
    unsigned* gmaxT = (unsigned*)(ws + 26400000);
    float*    gsum  = (float*)(ws + 26465536);
    unsigned* gcnt  = (unsigned*)(ws + 26531072);
    unsigned* degi  = (unsigned*)h;  // temp reuse before gemm1 overwrites h

    const int EB = (E + 255) / 256;
    const int NB = (N + 255) / 256;

    hipMemsetAsync(degi, 0, (size_t)N * 4, stream);
    k_deg<<<EB, 256, 0, stream>>>(colp, degi);
    k_dis<<<NB, 256, 0, stream>>>(degi, dis);

    k_gemm1<<<512, 256, 0, stream>>>(x, W1, h);

    hipMemsetAsync(agg, 0, (size_t)N * D * 4, stream);
    k_edge<<<EB, 256, 0, stream>>>(rowp, colp, dis, h, agg);
    k_combine1<<<NB, 256, 0, stream>>>(h, agg, dis, b1, g1, be1, m1, v1, W2);

    hipMemsetAsync(agg, 0, (size_t)N * D * 4, stream);
    k_edge<<<EB, 256, 0, stream>>>(rowp, colp, dis, h, agg);

    hipMemsetAsync(gmaxT, 0, (size_t)G * D * 4, stream);
    hipMemsetAsync(gsum, 0, (size_t)G * D * 4, stream);
    hipMemsetAsync(gcnt, 0, (size_t)G * 4, stream);
    k_combine2<<<NB, 256, 0, stream>>>(h, agg, dis, batch, b2, g2, be2, m2, v2,
                                       gmaxT, gsum, gcnt);

    k_head<<<(G + 255) / 256, 256, 0, stream>>>(gmaxT, gsum, gcnt, Wb, bb, Wm, bm, out);
}

// Round 2
// 1366.614 us; speedup vs baseline: 8.5718x; 8.5718x over previous
//
#include <hip/hip_runtime.h>
#include <math.h>

#define N   200000
#define E   6400000
#define IN_ 128
#define D   16
#define G   1024
#define BNEPS 1e-5f

#define SCAN_TILE 2048   // 256 threads * 8 items
#define SCAN_NB   98     // ceil(N / 2048)

// ---------- helpers ----------
__device__ __forceinline__ unsigned f2ord(float f) {
    unsigned b = __float_as_uint(f);
    return (b & 0x80000000u) ? ~b : (b | 0x80000000u);
}
__device__ __forceinline__ float ord2f(unsigned u) {
    return __uint_as_float((u & 0x80000000u) ? (u & 0x7FFFFFFFu) : ~u);
}

// ---------- degree count (in-degree by col) ----------
__global__ __launch_bounds__(256) void k_deg(const int* __restrict__ col,
                                             unsigned* __restrict__ degi) {
    int e = blockIdx.x * 256 + threadIdx.x;
    if (e < E) atomicAdd(&degi[col[e]], 1u);
}

__global__ __launch_bounds__(256) void k_dis(const unsigned* __restrict__ degi,
                                             float* __restrict__ dis) {
    int i = blockIdx.x * 256 + threadIdx.x;
    if (i < N) dis[i] = rsqrtf((float)degi[i] + 1.0f);
}

// ---------- scan: rowptr = exclusive_scan(degi) ----------
__global__ __launch_bounds__(256) void k_scan1(const unsigned* __restrict__ degi,
                                               unsigned* __restrict__ rowptr,
                                               unsigned* __restrict__ bsum) {
    __shared__ unsigned ts[256];
    int tid = threadIdx.x;
    int base = blockIdx.x * SCAN_TILE + tid * 8;
    unsigned v[8], s = 0;
#pragma unroll
    for (int t = 0; t < 8; t++) {
        int i = base + t;
        v[t] = (i < N) ? degi[i] : 0u;
        s += v[t];
    }
    ts[tid] = s;
    __syncthreads();
    for (int off = 1; off < 256; off <<= 1) {
        unsigned t2 = ts[tid];
        if (tid >= off) t2 += ts[tid - off];
        __syncthreads();
        ts[tid] = t2;
        __syncthreads();
    }
    unsigned run = (tid > 0) ? ts[tid - 1] : 0u;
#pragma unroll
    for (int t = 0; t < 8; t++) {
        int i = base + t;
        if (i < N) rowptr[i] = run;
        run += v[t];
    }
    if (tid == 255) bsum[blockIdx.x] = ts[255];
}

__global__ __launch_bounds__(128) void k_scan2(const unsigned* __restrict__ bsum,
                                               unsigned* __restrict__ boffs) {
    __shared__ unsigned ts[128];
    int tid = threadIdx.x;
    ts[tid] = (tid < SCAN_NB) ? bsum[tid] : 0u;
    __syncthreads();
    for (int off = 1; off < 128; off <<= 1) {
        unsigned t2 = ts[tid];
        if (tid >= off) t2 += ts[tid - off];
        __syncthreads();
        ts[tid] = t2;
        __syncthreads();
    }
    boffs[tid] = (tid > 0) ? ts[tid - 1] : 0u;
}

__global__ __launch_bounds__(256) void k_scan3(unsigned* __restrict__ rowptr,
                                               const unsigned* __restrict__ boffs,
                                               unsigned* __restrict__ cursor) {
    int i = blockIdx.x * 256 + threadIdx.x;
    if (i < N) {
        unsigned r = rowptr[i] + boffs[i / SCAN_TILE];
        rowptr[i] = r;
        cursor[i] = r;
    }
    if (i == 0) rowptr[N] = E;
}

// ---------- scatter edges into CSR-by-col: srcA[pos] = row ----------
__global__ __launch_bounds__(256) void k_scatter(const int* __restrict__ row,
                                                 const int* __restrict__ col,
                                                 unsigned* __restrict__ cursor,
                                                 int* __restrict__ srcA) {
    int e = blockIdx.x * 256 + threadIdx.x;
    if (e >= E) return;
    int c = col[e];
    unsigned pos = atomicAdd(&cursor[c], 1u);
    srcA[pos] = row[e];
}

// ---------- hs1 = (x @ W1) * dis  (N x 128 @ 128 x 16) ----------
__global__ __launch_bounds__(256) void k_gemm1(const float* __restrict__ x,
                                               const float* __restrict__ W1,
                                               const float* __restrict__ dis,
                                               float* __restrict__ hs) {
    __shared__ float Wls[IN_ * D];    // 8 KB
    __shared__ float xs[16 * 129];    // 16 rows, padded
    int tid = threadIdx.x;
    for (int i = tid; i < IN_ * D; i += 256) Wls[i] = W1[i];
    int g = tid >> 4, j = tid & 15;
    const int ntiles = N / 16;  // 12500 exact
    for (int t = blockIdx.x; t < ntiles; t += gridDim.x) {
        __syncthreads();
        int n0 = t * 16;
        for (int i = tid; i < 16 * IN_; i += 256) {
            xs[(i >> 7) * 129 + (i & 127)] = x[(size_t)n0 * IN_ + i];
        }
        __syncthreads();
        float acc = 0.f;
#pragma unroll
        for (int k = 0; k < IN_; k++) acc += xs[g * 129 + k] * Wls[k * D + j];
        hs[(size_t)(n0 + g) * D + j] = acc * dis[n0 + g];
    }
}

// ---------- layer1 gather + BN1/ReLU + GEMM2: hs2 = BN1(ReLU(dis*(sum hs1)+b1)) @ W2 * dis ----------
__global__ __launch_bounds__(256) void k_gather1(const unsigned* __restrict__ rowptr,
                                                 const int* __restrict__ srcA,
                                                 const float* __restrict__ dis,
                                                 const float* __restrict__ hs1,
                                                 const float* __restrict__ b1,
                                                 const float* __restrict__ g1,
                                                 const float* __restrict__ be1,
                                                 const float* __restrict__ m1,
                                                 const float* __restrict__ v1,
                                                 const float* __restrict__ W2,
                                                 float* __restrict__ hs2) {
    __shared__ float W2s[D * D];
    int tid = threadIdx.x;
    if (tid < D * D) W2s[tid] = W2[tid];
    __syncthreads();
    int i = blockIdx.x * 16 + (tid >> 4);
    int j = tid & 15;
    // i < N always: grid is exactly N/16 blocks
    unsigned start = rowptr[i], end = rowptr[i + 1];
    float sum = hs1[(size_t)i * D + j];   // self-loop term (dis already folded)
    unsigned k = start;
    for (; k + 1 < end; k += 2) {
        int s0 = srcA[k], s1 = srcA[k + 1];
        float a0 = hs1[(size_t)s0 * D + j];
        float a1 = hs1[(size_t)s1 * D + j];
        sum += a0 + a1;
    }
    if (k < end) sum += hs1[(size_t)srcA[k] * D + j];
    float di = dis[i];
    float t = di * sum + b1[j];
    t = fmaxf(t, 0.f);
    float sc = g1[j] * rsqrtf(v1[j] + BNEPS);
    float x1 = (t - m1[j]) * sc + be1[j];
    // GEMM2 across the 16-lane group via shuffles
    float acc = 0.f;
#pragma unroll
    for (int kk = 0; kk < D; kk++) {
        float v = __shfl(x1, kk, 16);
        acc += v * W2s[kk * D + j];
    }
    hs2[(size_t)i * D + j] = acc * di;
}

// ---------- layer2 gather + BN2/ReLU: x2 out ----------
__global__ __launch_bounds__(256) void k_gather2(const unsigned* __restrict__ rowptr,
                                                 const int* __restrict__ srcA,
                                                 const float* __restrict__ dis,
                                                 const float* __restrict__ hs2,
                                                 const float* __restrict__ b2,
                                                 const float* __restrict__ g2,
                                                 const float* __restrict__ be2,
                                                 const float* __restrict__ m2,
                                                 const float* __restrict__ v2,
                                                 float* __restrict__ x2) {
    int tid = threadIdx.x;
    int i = blockIdx.x * 16 + (tid >> 4);
    int j = tid & 15;
    unsigned start = rowptr[i], end = rowptr[i + 1];
    float sum = hs2[(size_t)i * D + j];
    unsigned k = start;
    for (; k + 1 < end; k += 2) {
        int s0 = srcA[k], s1 = srcA[k + 1];
        float a0 = hs2[(size_t)s0 * D + j];
        float a1 = hs2[(size_t)s1 * D + j];
        sum += a0 + a1;
    }
    if (k < end) sum += hs2[(size_t)srcA[k] * D + j];
    float t = dis[i] * sum + b2[j];
    t = fmaxf(t, 0.f);
    float sc = g2[j] * rsqrtf(v2[j] + BNEPS);
    x2[(size_t)i * D + j] = (t - m2[j]) * sc + be2[j];
}

// ---------- pooling: block-segmented reduction (batch is sorted) ----------
__global__ __launch_bounds__(256) void k_pool(const float* __restrict__ x2,
                                              const int* __restrict__ batch,
                                              unsigned* __restrict__ gmaxT,
                                              float* __restrict__ gsum,
                                              unsigned* __restrict__ gcnt) {
    __shared__ unsigned smax[32 * D];
    __shared__ float ssum[32 * D];
    __shared__ unsigned scnt[32];
    int tid = threadIdx.x;
    for (int s = tid; s < 32 * D; s += 256) { smax[s] = 0u; ssum[s] = 0.f; }
    if (tid < 32) scnt[tid] = 0u;
    __syncthreads();
    int n = blockIdx.x * 256 + tid;
    int g0 = batch[blockIdx.x * 256];  // block start always < N
    if (n < N) {
        int lg = batch[n] - g0;
        const float* xp = x2 + (size_t)n * D;
        if (lg < 32) {
            atomicAdd(&scnt[lg], 1u);
#pragma unroll
            for (int j = 0; j < D; j++) {
                float v = xp[j];
                atomicMax(&smax[lg * D + j], f2ord(v));
                atomicAdd(&ssum[lg * D + j], v);
            }
        } else {  // pathological fallback
            int g = batch[n];
            atomicAdd(&gcnt[g], 1u);
#pragma unroll
            for (int j = 0; j < D; j++) {
                float v = xp[j];
                atomicMax(&gmaxT[(size_t)g * D + j], f2ord(v));
                atomicAdd(&gsum[(size_t)g * D + j], v);
            }
        }
    }
    __syncthreads();
    for (int s = tid; s < 32 * D; s += 256) {
        int slot = s >> 4, j = s & 15;
        if (scnt[slot] > 0u) {
            int g = g0 + slot;
            atomicMax(&gmaxT[(size_t)g * D + j], smax[s]);
            atomicAdd(&gsum[(size_t)g * D + j], ssum[s]);
            if (j == 0) atomicAdd(&gcnt[g], scnt[slot]);
        }
    }
}

// ---------- head ----------
__global__ __launch_bounds__(256) void k_head(const unsigned* __restrict__ gmaxT,
                                              const float* __restrict__ gsum,
                                              const unsigned* __restrict__ gcnt,
                                              const float* __restrict__ Wb,
                                              const float* __restrict__ bb,
                                              const float* __restrict__ Wm,
                                              const float* __restrict__ bm,
                                              float* __restrict__ out) {
    __shared__ float Wbs[32 * 16];
    __shared__ float bbs[16], Wms[16];
    __shared__ float bm0;
    int tid = threadIdx.x;
    for (int i = tid; i < 32 * 16; i += 256) Wbs[i] = Wb[i];
    if (tid < 16) { bbs[tid] = bb[tid]; Wms[tid] = Wm[tid]; }
    if (tid == 0) bm0 = bm[0];
    __syncthreads();
    int g = blockIdx.x * 256 + tid;
    if (g >= G) return;
    float in[32];
    float inv = 1.0f / (float)gcnt[g];
#pragma unroll
    for (int j = 0; j < D; j++) {
        in[j] = ord2f(gmaxT[(size_t)g * D + j]);
        in[16 + j] = gsum[(size_t)g * D + j] * inv;
    }
    float z = bm0;
#pragma unroll
    for (int j = 0; j < 16; j++) {
        float acc = bbs[j];
#pragma unroll
        for (int k = 0; k < 32; k++) acc += in[k] * Wbs[k * 16 + j];
        acc = fmaxf(acc, 0.f);
        z += acc * Wms[j];
    }
    out[g] = 1.0f / (1.0f + expf(-z));
}

extern "C" void kernel_launch(void* const* d_in, const int* in_sizes, int n_in,
                              void* d_out, int out_size, void* d_ws, size_t ws_size,
                              hipStream_t stream) {
    const float* x   = (const float*)d_in[0];
    const int* ei    = (const int*)d_in[1];
    const int* rowp  = ei;
    const int* colp  = ei + E;
    const int* batch = (const int*)d_in[2];
    const float* W1  = (const float*)d_in[3];
    const float* b1  = (const float*)d_in[4];
    const float* g1  = (const float*)d_in[5];
    const float* be1 = (const float*)d_in[6];
    const float* m1  = (const float*)d_in[7];
    const float* v1  = (const float*)d_in[8];
    const float* W2  = (const float*)d_in[9];
    const float* b2  = (const float*)d_in[10];
    const float* g2  = (const float*)d_in[11];
    const float* be2 = (const float*)d_in[12];
    const float* m2  = (const float*)d_in[13];
    const float* v2  = (const float*)d_in[14];
    const float* Wb  = (const float*)d_in[15];
    const float* bb  = (const float*)d_in[16];
    const float* Wm  = (const float*)d_in[17];
    const float* bm  = (const float*)d_in[18];
    float* out = (float*)d_out;

    char* ws = (char*)d_ws;
    // layout (bytes):
    unsigned* rowptr = (unsigned*)(ws);               // (N+1) u32, pad to 802816
    unsigned* cursor = (unsigned*)(ws + 802816);      // N u32
    unsigned* degi   = (unsigned*)(ws + 1605632);     // N u32
    float*    dis    = (float*)   (ws + 2408448);     // N f32
    unsigned* bsum   = (unsigned*)(ws + 3211264);     // 128 u32
    unsigned* boffs  = (unsigned*)(ws + 3211776);     // 128 u32
    unsigned* gmaxT  = (unsigned*)(ws + 3212288);     // G*D u32
    float*    gsum   = (float*)   (ws + 3277824);     // G*D f32
    unsigned* gcnt   = (unsigned*)(ws + 3343360);     // G u32
    int*      srcA   = (int*)     (ws + 3347456);     // E i32 (25.6 MB)
    float*    hs1    = (float*)   (ws + 28947456);    // N*D f32 (12.8 MB)
    float*    hs2    = (float*)   (ws + 41747456);    // N*D f32 (12.8 MB)
    float*    x2buf  = hs1;                           // reuse after gather1

    const int EB = (E + 255) / 256;
    const int NB = (N + 255) / 256;

    hipMemsetAsync(degi, 0, (size_t)N * 4, stream);
    hipMemsetAsync(gmaxT, 0, (size_t)G * D * 4, stream);
    hipMemsetAsync(gsum, 0, (size_t)G * D * 4, stream);
    hipMemsetAsync(gcnt, 0, (size_t)G * 4, stream);

    k_deg<<<EB, 256, 0, stream>>>(colp, degi);
    k_dis<<<NB, 256, 0, stream>>>(degi, dis);
    k_scan1<<<SCAN_NB, 256, 0, stream>>>(degi, rowptr, bsum);
    k_scan2<<<1, 128, 0, stream>>>(bsum, boffs);
    k_scan3<<<NB, 256, 0, stream>>>(rowptr, boffs, cursor);
    k_scatter<<<EB, 256, 0, stream>>>(rowp, colp, cursor, srcA);

    k_gemm1<<<512, 256, 0, stream>>>(x, W1, dis, hs1);

    k_gather1<<<N / 16, 256, 0, stream>>>(rowptr, srcA, dis, hs1,
                                          b1, g1, be1, m1, v1, W2, hs2);
    k_gather2<<<N / 16, 256, 0, stream>>>(rowptr, srcA, dis, hs2,
                                          b2, g2, be2, m2, v2, x2buf);

    k_pool<<<NB, 256, 0, stream>>>(x2buf, batch, gmaxT, gsum, gcnt);
    k_head<<<(G + 255) / 256, 256, 0, stream>>>(gmaxT, gsum, gcnt, Wb, bb, Wm, bm, out);
}

// Round 3
// 725.449 us; speedup vs baseline: 16.1478x; 1.8838x over previous
//
#include <hip/hip_runtime.h>
#include <math.h>

#define N   200000
#define E   6400000
#define IN_ 128
#define D   16
#define G   1024
#define BNEPS 1e-5f

#define BSH   9                      // 512 cols per bucket
#define NBKT  391                    // ceil(N / 512)
#define CH    8192                   // edges per k_bin block
#define BINB  782                    // ceil(E / CH)

// ---------- helpers ----------
__device__ __forceinline__ unsigned f2ord(float f) {
    unsigned b = __float_as_uint(f);
    return (b & 0x80000000u) ? ~b : (b | 0x80000000u);
}
__device__ __forceinline__ float ord2f(unsigned u) {
    return __uint_as_float((u & 0x80000000u) ? (u & 0x7FFFFFFFu) : ~u);
}

// ---------- bucket histogram ----------
__global__ __launch_bounds__(256) void k_hist(const int* __restrict__ col,
                                              unsigned* __restrict__ bucketCnt) {
    __shared__ unsigned h[NBKT];
    for (int i = threadIdx.x; i < NBKT; i += 256) h[i] = 0u;
    __syncthreads();
    int stride = gridDim.x * 256;
    for (int e = blockIdx.x * 256 + threadIdx.x; e < E; e += stride)
        atomicAdd(&h[col[e] >> BSH], 1u);
    __syncthreads();
    for (int i = threadIdx.x; i < NBKT; i += 256)
        if (h[i]) atomicAdd(&bucketCnt[i], h[i]);
}

// ---------- scan bucket counts -> bucketBase / cursorB ----------
__global__ __launch_bounds__(512) void k_bscan(const unsigned* __restrict__ bucketCnt,
                                               unsigned* __restrict__ bucketBase,
                                               unsigned* __restrict__ cursorB,
                                               unsigned* __restrict__ rowptr) {
    __shared__ unsigned s[512];
    int t = threadIdx.x;
    s[t] = (t < NBKT) ? bucketCnt[t] : 0u;
    __syncthreads();
    for (int off = 1; off < 512; off <<= 1) {
        unsigned v = (t >= off) ? s[t - off] : 0u;
        __syncthreads();
        s[t] += v;
        __syncthreads();
    }
    unsigned excl = (t > 0) ? s[t - 1] : 0u;
    if (t <= NBKT) {
        bucketBase[t] = excl;      // t==NBKT -> s[NBKT-1] == E
        cursorB[t] = excl;
    }
    if (t == 0) rowptr[N] = E;
}

// ---------- phase 1: bin edges by bucket, coalesced run writes ----------
// packed record: row (18 bits) | col_low9 << 18
__global__ __launch_bounds__(256) void k_bin(const int* __restrict__ row,
                                             const int* __restrict__ col,
                                             unsigned* __restrict__ cursorB,
                                             unsigned* __restrict__ tmp) {
    __shared__ unsigned hist[NBKT];
    __shared__ unsigned lbase[NBKT];
    __shared__ unsigned lcur[NBKT];
    __shared__ unsigned gbase[NBKT];
    __shared__ unsigned sscan[512];
    __shared__ unsigned sbuf[CH];
    __shared__ unsigned short sbkt[CH];
    int tid = threadIdx.x;
    int base = blockIdx.x * CH;
    int cnt = min(CH, E - base);
    for (int i = tid; i < NBKT; i += 256) hist[i] = 0u;
    __syncthreads();
    for (int i = tid; i < cnt; i += 256)
        atomicAdd(&hist[col[base + i] >> BSH], 1u);
    __syncthreads();
    // exclusive scan of hist (391 <= 512), 2 elems/thread Hillis-Steele
    sscan[tid]       = (tid < NBKT) ? hist[tid] : 0u;
    sscan[tid + 256] = (tid + 256 < NBKT) ? hist[tid + 256] : 0u;
    __syncthreads();
    for (int off = 1; off < 512; off <<= 1) {
        unsigned v0 = (tid >= off) ? sscan[tid - off] : 0u;
        unsigned v1 = (tid + 256 >= off) ? sscan[tid + 256 - off] : 0u;
        __syncthreads();
        sscan[tid] += v0;
        sscan[tid + 256] += v1;
        __syncthreads();
    }
    if (tid < NBKT) {
        unsigned e0 = (tid > 0) ? sscan[tid - 1] : 0u;
        lbase[tid] = e0; lcur[tid] = e0;
    }
    if (tid + 256 < NBKT) {
        unsigned e1 = sscan[tid + 255];
        lbase[tid + 256] = e1; lcur[tid + 256] = e1;
    }
    __syncthreads();
    // reserve global runs (one atomic per nonempty bucket)
    for (int b = tid; b < NBKT; b += 256) {
        unsigned c = hist[b];
        if (c) gbase[b] = atomicAdd(&cursorB[b], c);
    }
    // reorder records into LDS grouped by bucket
    for (int i = tid; i < cnt; i += 256) {
        int c = col[base + i];
        int r = row[base + i];
        int b = c >> BSH;
        unsigned p = atomicAdd(&lcur[b], 1u);
        sbuf[p] = (unsigned)r | ((unsigned)(c & ((1 << BSH) - 1)) << 18);
        sbkt[p] = (unsigned short)b;
    }
    __syncthreads();
    // coalesced run copy-out
    for (int i = tid; i < cnt; i += 256) {
        int b = sbkt[i];
        tmp[gbase[b] + (unsigned)i - lbase[b]] = sbuf[i];
    }
}

// ---------- phase 2: per-bucket counting sort -> srcA, rowptr, dis ----------
__global__ __launch_bounds__(512) void k_bsort(const unsigned* __restrict__ bucketBase,
                                               const unsigned* __restrict__ tmp,
                                               unsigned* __restrict__ rowptr,
                                               float* __restrict__ dis,
                                               int* __restrict__ srcA) {
    __shared__ unsigned cnt[512];
    __shared__ unsigned offs[512];
    __shared__ unsigned lcur[512];
    int tid = threadIdx.x;
    int b = blockIdx.x;
    unsigned s0 = bucketBase[b], s1 = bucketBase[b + 1];
    cnt[tid] = 0u;
    __syncthreads();
    for (unsigned i = s0 + tid; i < s1; i += 512)
        atomicAdd(&cnt[tmp[i] >> 18], 1u);
    __syncthreads();
    offs[tid] = cnt[tid];
    __syncthreads();
    for (int off = 1; off < 512; off <<= 1) {
        unsigned v = (tid >= off) ? offs[tid - off] : 0u;
        __syncthreads();
        offs[tid] += v;
        __syncthreads();
    }
    unsigned excl = (tid > 0) ? offs[tid - 1] : 0u;
    int c = (b << BSH) + tid;
    if (c < N) {
        rowptr[c] = s0 + excl;
        dis[c] = rsqrtf((float)cnt[tid] + 1.0f);
    }
    lcur[tid] = s0 + excl;
    __syncthreads();
    for (unsigned i = s0 + tid; i < s1; i += 512) {
        unsigned p = tmp[i];
        unsigned pos = atomicAdd(&lcur[p >> 18], 1u);
        srcA[pos] = (int)(p & 0x3FFFFu);
    }
}

// ---------- hs1 = (x @ W1) * dis ----------
__global__ __launch_bounds__(256) void k_gemm1(const float* __restrict__ x,
                                               const float* __restrict__ W1,
                                               const float* __restrict__ dis,
                                               float* __restrict__ hs) {
    __shared__ float Wls[IN_ * D];
    __shared__ float xs[16 * 129];
    int tid = threadIdx.x;
    for (int i = tid; i < IN_ * D; i += 256) Wls[i] = W1[i];
    int g = tid >> 4, j = tid & 15;
    const int ntiles = N / 16;
    for (int t = blockIdx.x; t < ntiles; t += gridDim.x) {
        __syncthreads();
        int n0 = t * 16;
        for (int i = tid; i < 16 * IN_; i += 256) {
            xs[(i >> 7) * 129 + (i & 127)] = x[(size_t)n0 * IN_ + i];
        }
        __syncthreads();
        float acc = 0.f;
#pragma unroll
        for (int k = 0; k < IN_; k++) acc += xs[g * 129 + k] * Wls[k * D + j];
        hs[(size_t)(n0 + g) * D + j] = acc * dis[n0 + g];
    }
}

// ---------- layer1 gather + BN1/ReLU + GEMM2 ----------
__global__ __launch_bounds__(256) void k_gather1(const unsigned* __restrict__ rowptr,
                                                 const int* __restrict__ srcA,
                                                 const float* __restrict__ dis,
                                                 const float* __restrict__ hs1,
                                                 const float* __restrict__ b1,
                                                 const float* __restrict__ g1,
                                                 const float* __restrict__ be1,
                                                 const float* __restrict__ m1,
                                                 const float* __restrict__ v1,
                                                 const float* __restrict__ W2,
                                                 float* __restrict__ hs2) {
    __shared__ float W2s[D * D];
    int tid = threadIdx.x;
    if (tid < D * D) W2s[tid] = W2[tid];
    __syncthreads();
    int i = blockIdx.x * 16 + (tid >> 4);
    int j = tid & 15;
    unsigned start = rowptr[i], end = rowptr[i + 1];
    float sum = hs1[(size_t)i * D + j];
    unsigned k = start;
    for (; k + 1 < end; k += 2) {
        int s0 = srcA[k], s1 = srcA[k + 1];
        float a0 = hs1[(size_t)s0 * D + j];
        float a1 = hs1[(size_t)s1 * D + j];
        sum += a0 + a1;
    }
    if (k < end) sum += hs1[(size_t)srcA[k] * D + j];
    float di = dis[i];
    float t = di * sum + b1[j];
    t = fmaxf(t, 0.f);
    float sc = g1[j] * rsqrtf(v1[j] + BNEPS);
    float x1 = (t - m1[j]) * sc + be1[j];
    float acc = 0.f;
#pragma unroll
    for (int kk = 0; kk < D; kk++) {
        float v = __shfl(x1, kk, 16);
        acc += v * W2s[kk * D + j];
    }
    hs2[(size_t)i * D + j] = acc * di;
}

// ---------- layer2 gather + BN2/ReLU ----------
__global__ __launch_bounds__(256) void k_gather2(const unsigned* __restrict__ rowptr,
                                                 const int* __restrict__ srcA,
                                                 const float* __restrict__ dis,
                                                 const float* __restrict__ hs2,
                                                 const float* __restrict__ b2,
                                                 const float* __restrict__ g2,
                                                 const float* __restrict__ be2,
                                                 const float* __restrict__ m2,
                                                 const float* __restrict__ v2,
                                                 float* __restrict__ x2) {
    int tid = threadIdx.x;
    int i = blockIdx.x * 16 + (tid >> 4);
    int j = tid & 15;
    unsigned start = rowptr[i], end = rowptr[i + 1];
    float sum = hs2[(size_t)i * D + j];
    unsigned k = start;
    for (; k + 1 < end; k += 2) {
        int s0 = srcA[k], s1 = srcA[k + 1];
        float a0 = hs2[(size_t)s0 * D + j];
        float a1 = hs2[(size_t)s1 * D + j];
        sum += a0 + a1;
    }
    if (k < end) sum += hs2[(size_t)srcA[k] * D + j];
    float t = dis[i] * sum + b2[j];
    t = fmaxf(t, 0.f);
    float sc = g2[j] * rsqrtf(v2[j] + BNEPS);
    x2[(size_t)i * D + j] = (t - m2[j]) * sc + be2[j];
}

// ---------- pooling ----------
__global__ __launch_bounds__(256) void k_pool(const float* __restrict__ x2,
                                              const int* __restrict__ batch,
                                              unsigned* __restrict__ gmaxT,
                                              float* __restrict__ gsum,
                                              unsigned* __restrict__ gcnt) {
    __shared__ unsigned smax[32 * D];
    __shared__ float ssum[32 * D];
    __shared__ unsigned scnt[32];
    int tid = threadIdx.x;
    for (int s = tid; s < 32 * D; s += 256) { smax[s] = 0u; ssum[s] = 0.f; }
    if (tid < 32) scnt[tid] = 0u;
    __syncthreads();
    int n = blockIdx.x * 256 + tid;
    int g0 = batch[blockIdx.x * 256];
    if (n < N) {
        int lg = batch[n] - g0;
        const float* xp = x2 + (size_t)n * D;
        if (lg < 32) {
            atomicAdd(&scnt[lg], 1u);
#pragma unroll
            for (int j = 0; j < D; j++) {
                float v = xp[j];
                atomicMax(&smax[lg * D + j], f2ord(v));
                atomicAdd(&ssum[lg * D + j], v);
            }
        } else {
            int g = batch[n];
            atomicAdd(&gcnt[g], 1u);
#pragma unroll
            for (int j = 0; j < D; j++) {
                float v = xp[j];
                atomicMax(&gmaxT[(size_t)g * D + j], f2ord(v));
                atomicAdd(&gsum[(size_t)g * D + j], v);
            }
        }
    }
    __syncthreads();
    for (int s = tid; s < 32 * D; s += 256) {
        int slot = s >> 4, j = s & 15;
        if (scnt[slot] > 0u) {
            int g = g0 + slot;
            atomicMax(&gmaxT[(size_t)g * D + j], smax[s]);
            atomicAdd(&gsum[(size_t)g * D + j], ssum[s]);
            if (j == 0) atomicAdd(&gcnt[g], scnt[slot]);
        }
    }
}

// ---------- head ----------
__global__ __launch_bounds__(256) void k_head(const unsigned* __restrict__ gmaxT,
                                              const float* __restrict__ gsum,
                                              const unsigned* __restrict__ gcnt,
                                              const float* __restrict__ Wb,
                                              const float* __restrict__ bb,
                                              const float* __restrict__ Wm,
                                              const float* __restrict__ bm,
                                              float* __restrict__ out) {
    __shared__ float Wbs[32 * 16];
    __shared__ float bbs[16], Wms[16];
    __shared__ float bm0;
    int tid = threadIdx.x;
    for (int i = tid; i < 32 * 16; i += 256) Wbs[i] = Wb[i];
    if (tid < 16) { bbs[tid] = bb[tid]; Wms[tid] = Wm[tid]; }
    if (tid == 0) bm0 = bm[0];
    __syncthreads();
    int g = blockIdx.x * 256 + tid;
    if (g >= G) return;
    float in[32];
    float inv = 1.0f / (float)gcnt[g];
#pragma unroll
    for (int j = 0; j < D; j++) {
        in[j] = ord2f(gmaxT[(size_t)g * D + j]);
        in[16 + j] = gsum[(size_t)g * D + j] * inv;
    }
    float z = bm0;
#pragma unroll
    for (int j = 0; j < 16; j++) {
        float acc = bbs[j];
#pragma unroll
        for (int k = 0; k < 32; k++) acc += in[k] * Wbs[k * 16 + j];
        acc = fmaxf(acc, 0.f);
        z += acc * Wms[j];
    }
    out[g] = 1.0f / (1.0f + expf(-z));
}

extern "C" void kernel_launch(void* const* d_in, const int* in_sizes, int n_in,
                              void* d_out, int out_size, void* d_ws, size_t ws_size,
                              hipStream_t stream) {
    const float* x   = (const float*)d_in[0];
    const int* ei    = (const int*)d_in[1];
    const int* rowp  = ei;
    const int* colp  = ei + E;
    const int* batch = (const int*)d_in[2];
    const float* W1  = (const float*)d_in[3];
    const float* b1  = (const float*)d_in[4];
    const float* g1  = (const float*)d_in[5];
    const float* be1 = (const float*)d_in[6];
    const float* m1  = (const float*)d_in[7];
    const float* v1  = (const float*)d_in[8];
    const float* W2  = (const float*)d_in[9];
    const float* b2  = (const float*)d_in[10];
    const float* g2  = (const float*)d_in[11];
    const float* be2 = (const float*)d_in[12];
    const float* m2  = (const float*)d_in[13];
    const float* v2  = (const float*)d_in[14];
    const float* Wb  = (const float*)d_in[15];
    const float* bb  = (const float*)d_in[16];
    const float* Wm  = (const float*)d_in[17];
    const float* bm  = (const float*)d_in[18];
    float* out = (float*)d_out;

    char* ws = (char*)d_ws;
    // layout (bytes):
    int*      srcA   = (int*)     (ws);                // E i32            [0, 25.6M)
    unsigned* tmp    = (unsigned*)(ws + 25600000);     // E u32 packed     [25.6M, 51.2M)
    float*    hs1    = (float*)   (ws + 25600000);     // N*D f32 — overlays tmp AFTER k_bsort
    float*    hs2    = (float*)   (ws + 38400000);     // N*D f32 — overlays tmp tail
    unsigned* rowptr = (unsigned*)(ws + 51200000);     // (N+1) u32
    float*    dis    = (float*)   (ws + 52000016);     // N f32
    unsigned* bucketCnt  = (unsigned*)(ws + 52800016); // NBKT+1 u32
    unsigned* bucketBase = (unsigned*)(ws + 52801600); // NBKT+1 u32
    unsigned* cursorB    = (unsigned*)(ws + 52803200); // NBKT+1 u32
    unsigned* gmaxT  = (unsigned*)(ws + 52804800);     // G*D u32
    float*    gsum   = (float*)   (ws + 52870336);     // G*D f32
    unsigned* gcnt   = (unsigned*)(ws + 52935872);     // G u32
    float*    x2buf  = hs1;                            // reuse after gather1

    const int NB = (N + 255) / 256;

    hipMemsetAsync(bucketCnt, 0, (NBKT + 1) * 4, stream);
    hipMemsetAsync(gmaxT, 0, (size_t)G * D * 4, stream);
    hipMemsetAsync(gsum, 0, (size_t)G * D * 4, stream);
    hipMemsetAsync(gcnt, 0, (size_t)G * 4, stream);

    k_hist<<<1024, 256, 0, stream>>>(colp, bucketCnt);
    k_bscan<<<1, 512, 0, stream>>>(bucketCnt, bucketBase, cursorB, rowptr);
    k_bin<<<BINB, 256, 0, stream>>>(rowp, colp, cursorB, tmp);
    k_bsort<<<NBKT, 512, 0, stream>>>(bucketBase, tmp, rowptr, dis, srcA);

    k_gemm1<<<512, 256, 0, stream>>>(x, W1, dis, hs1);

    k_gather1<<<N / 16, 256, 0, stream>>>(rowptr, srcA, dis, hs1,
                                          b1, g1, be1, m1, v1, W2, hs2);
    k_gather2<<<N / 16, 256, 0, stream>>>(rowptr, srcA, dis, hs2,
                                          b2, g2, be2, m2, v2, x2buf);

    k_pool<<<NB, 256, 0, stream>>>(x2buf, batch, gmaxT, gsum, gcnt);
    k_head<<<(G + 255) / 256, 256, 0, stream>>>(gmaxT, gsum, gcnt, Wb, bb, Wm, bm, out);
}

// Round 4
// 568.832 us; speedup vs baseline: 20.5937x; 1.2753x over previous
//
#include <hip/hip_runtime.h>
#include <math.h>

#define N   200000
#define E   6400000
#define IN_ 128
#define D   16
#define G   1024
#define BNEPS 1e-5f

#define BSH   9                      // 512 cols per bucket
#define NBKT  391                    // ceil(N / 512)
#define CH    8192                   // edges per k_bin block
#define BINB  782                    // ceil(E / CH)

typedef _Float16 f16;
typedef __attribute__((ext_vector_type(8))) _Float16 f16x8;
typedef __attribute__((ext_vector_type(4))) float f32x4;

// ---------- helpers ----------
__device__ __forceinline__ unsigned f2ord(float f) {
    unsigned b = __float_as_uint(f);
    return (b & 0x80000000u) ? ~b : (b | 0x80000000u);
}
__device__ __forceinline__ float ord2f(unsigned u) {
    return __uint_as_float((u & 0x80000000u) ? (u & 0x7FFFFFFFu) : ~u);
}

// ---------- bucket histogram ----------
__global__ __launch_bounds__(256) void k_hist(const int* __restrict__ col,
                                              unsigned* __restrict__ bucketCnt) {
    __shared__ unsigned h[NBKT];
    for (int i = threadIdx.x; i < NBKT; i += 256) h[i] = 0u;
    __syncthreads();
    int stride = gridDim.x * 256;
    for (int e = blockIdx.x * 256 + threadIdx.x; e < E; e += stride)
        atomicAdd(&h[col[e] >> BSH], 1u);
    __syncthreads();
    for (int i = threadIdx.x; i < NBKT; i += 256)
        if (h[i]) atomicAdd(&bucketCnt[i], h[i]);
}

// ---------- scan bucket counts ----------
__global__ __launch_bounds__(512) void k_bscan(const unsigned* __restrict__ bucketCnt,
                                               unsigned* __restrict__ bucketBase,
                                               unsigned* __restrict__ cursorB,
                                               unsigned* __restrict__ rowptr) {
    __shared__ unsigned s[512];
    int t = threadIdx.x;
    s[t] = (t < NBKT) ? bucketCnt[t] : 0u;
    __syncthreads();
    for (int off = 1; off < 512; off <<= 1) {
        unsigned v = (t >= off) ? s[t - off] : 0u;
        __syncthreads();
        s[t] += v;
        __syncthreads();
    }
    unsigned excl = (t > 0) ? s[t - 1] : 0u;
    if (t <= NBKT) {
        bucketBase[t] = excl;
        cursorB[t] = excl;
    }
    if (t == 0) rowptr[N] = E;
}

// ---------- phase 1: bin edges by bucket ----------
__global__ __launch_bounds__(256) void k_bin(const int* __restrict__ row,
                                             const int* __restrict__ col,
                                             unsigned* __restrict__ cursorB,
                                             unsigned* __restrict__ tmp) {
    __shared__ unsigned hist[NBKT];
    __shared__ unsigned lbase[NBKT];
    __shared__ unsigned lcur[NBKT];
    __shared__ unsigned gbase[NBKT];
    __shared__ unsigned sscan[512];
    __shared__ unsigned sbuf[CH];
    __shared__ unsigned short sbkt[CH];
    int tid = threadIdx.x;
    int base = blockIdx.x * CH;
    int cnt = min(CH, E - base);
    for (int i = tid; i < NBKT; i += 256) hist[i] = 0u;
    __syncthreads();
    for (int i = tid; i < cnt; i += 256)
        atomicAdd(&hist[col[base + i] >> BSH], 1u);
    __syncthreads();
    sscan[tid]       = (tid < NBKT) ? hist[tid] : 0u;
    sscan[tid + 256] = (tid + 256 < NBKT) ? hist[tid + 256] : 0u;
    __syncthreads();
    for (int off = 1; off < 512; off <<= 1) {
        unsigned v0 = (tid >= off) ? sscan[tid - off] : 0u;
        unsigned v1 = (tid + 256 >= off) ? sscan[tid + 256 - off] : 0u;
        __syncthreads();
        sscan[tid] += v0;
        sscan[tid + 256] += v1;
        __syncthreads();
    }
    if (tid < NBKT) {
        unsigned e0 = (tid > 0) ? sscan[tid - 1] : 0u;
        lbase[tid] = e0; lcur[tid] = e0;
    }
    if (tid + 256 < NBKT) {
        unsigned e1 = sscan[tid + 255];
        lbase[tid + 256] = e1; lcur[tid + 256] = e1;
    }
    __syncthreads();
    for (int b = tid; b < NBKT; b += 256) {
        unsigned c = hist[b];
        if (c) gbase[b] = atomicAdd(&cursorB[b], c);
    }
    for (int i = tid; i < cnt; i += 256) {
        int c = col[base + i];
        int r = row[base + i];
        int b = c >> BSH;
        unsigned p = atomicAdd(&lcur[b], 1u);
        sbuf[p] = (unsigned)r | ((unsigned)(c & ((1 << BSH) - 1)) << 18);
        sbkt[p] = (unsigned short)b;
    }
    __syncthreads();
    for (int i = tid; i < cnt; i += 256) {
        int b = sbkt[i];
        tmp[gbase[b] + (unsigned)i - lbase[b]] = sbuf[i];
    }
}

// ---------- phase 2: per-bucket counting sort ----------
__global__ __launch_bounds__(512) void k_bsort(const unsigned* __restrict__ bucketBase,
                                               const unsigned* __restrict__ tmp,
                                               unsigned* __restrict__ rowptr,
                                               float* __restrict__ dis,
                                               int* __restrict__ srcA) {
    __shared__ unsigned cnt[512];
    __shared__ unsigned offs[512];
    __shared__ unsigned lcur[512];
    int tid = threadIdx.x;
    int b = blockIdx.x;
    unsigned s0 = bucketBase[b], s1 = bucketBase[b + 1];
    cnt[tid] = 0u;
    __syncthreads();
    for (unsigned i = s0 + tid; i < s1; i += 512)
        atomicAdd(&cnt[tmp[i] >> 18], 1u);
    __syncthreads();
    offs[tid] = cnt[tid];
    __syncthreads();
    for (int off = 1; off < 512; off <<= 1) {
        unsigned v = (tid >= off) ? offs[tid - off] : 0u;
        __syncthreads();
        offs[tid] += v;
        __syncthreads();
    }
    unsigned excl = (tid > 0) ? offs[tid - 1] : 0u;
    int c = (b << BSH) + tid;
    if (c < N) {
        rowptr[c] = s0 + excl;
        dis[c] = rsqrtf((float)cnt[tid] + 1.0f);
    }
    lcur[tid] = s0 + excl;
    __syncthreads();
    for (unsigned i = s0 + tid; i < s1; i += 512) {
        unsigned p = tmp[i];
        unsigned pos = atomicAdd(&lcur[p >> 18], 1u);
        srcA[pos] = (int)(p & 0x3FFFFu);
    }
}

// ---------- hs1 = f16((x @ W1) * dis) via MFMA 16x16x32 f16 ----------
__global__ __launch_bounds__(256) void k_gemm1(const float* __restrict__ x,
                                               const float* __restrict__ W1,
                                               const float* __restrict__ dis,
                                               f16* __restrict__ hs) {
    __shared__ f16 Wh[IN_ * D];   // 4 KB
    int tid = threadIdx.x;
    for (int i = tid; i < IN_ * D; i += 256) Wh[i] = (f16)W1[i];
    __syncthreads();
    int lane = tid & 63;
    int wave = tid >> 6;
    int m = lane & 15, quad = lane >> 4;
    // B fragments persist in registers: B[k = s*32 + quad*8 + jj][n = m]
    f16x8 bfrag[4];
#pragma unroll
    for (int s = 0; s < 4; s++)
#pragma unroll
        for (int jj = 0; jj < 8; jj++)
            bfrag[s][jj] = Wh[(s * 32 + quad * 8 + jj) * D + m];
    int gwave = blockIdx.x * 4 + wave;
    int nwaves = gridDim.x * 4;
    const int ntiles = N / 16;  // 12500 exact
    for (int t = gwave; t < ntiles; t += nwaves) {
        int n0 = t * 16;
        const float* xrow = x + (size_t)(n0 + m) * IN_ + quad * 8;
        f32x4 acc = {0.f, 0.f, 0.f, 0.f};
#pragma unroll
        for (int s = 0; s < 4; s++) {
            float4 lo = *(const float4*)(xrow + s * 32);
            float4 hi = *(const float4*)(xrow + s * 32 + 4);
            f16x8 a;
            a[0] = (f16)lo.x; a[1] = (f16)lo.y; a[2] = (f16)lo.z; a[3] = (f16)lo.w;
            a[4] = (f16)hi.x; a[5] = (f16)hi.y; a[6] = (f16)hi.z; a[7] = (f16)hi.w;
            acc = __builtin_amdgcn_mfma_f32_16x16x32_f16(a, bfrag[s], acc, 0, 0, 0);
        }
        // D: col = m, row = quad*4 + r
#pragma unroll
        for (int r = 0; r < 4; r++) {
            int rowi = n0 + quad * 4 + r;
            hs[(size_t)rowi * D + m] = (f16)(acc[r] * dis[rowi]);
        }
    }
}

// ---------- layer1 gather + BN1/ReLU + GEMM2 ----------
__global__ __launch_bounds__(256) void k_gather1(const unsigned* __restrict__ rowptr,
                                                 const int* __restrict__ srcA,
                                                 const float* __restrict__ dis,
                                                 const f16* __restrict__ hs1,
                                                 const float* __restrict__ b1,
                                                 const float* __restrict__ g1,
                                                 const float* __restrict__ be1,
                                                 const float* __restrict__ m1,
                                                 const float* __restrict__ v1,
                                                 const float* __restrict__ W2,
                                                 f16* __restrict__ hs2) {
    __shared__ float W2s[D * D];
    int tid = threadIdx.x;
    if (tid < D * D) W2s[tid] = W2[tid];
    __syncthreads();
    int i = blockIdx.x * 16 + (tid >> 4);
    int j = tid & 15;
    unsigned start = rowptr[i], end = rowptr[i + 1];
    float s0 = (float)hs1[(size_t)i * D + j];  // self-loop
    float s1 = 0.f, s2 = 0.f, s3 = 0.f;
    for (unsigned base = start; base < end; base += 16) {
        int idx = (int)base + j;
        int my = (idx < (int)end) ? srcA[idx] : 0;
        int cnt = min(16, (int)(end - base));
        int t = 0;
        for (; t + 4 <= cnt; t += 4) {
            int a = __shfl(my, t, 16);
            int b = __shfl(my, t + 1, 16);
            int c = __shfl(my, t + 2, 16);
            int d = __shfl(my, t + 3, 16);
            s0 += (float)hs1[(size_t)a * D + j];
            s1 += (float)hs1[(size_t)b * D + j];
            s2 += (float)hs1[(size_t)c * D + j];
            s3 += (float)hs1[(size_t)d * D + j];
        }
        for (; t < cnt; t++) {
            int a = __shfl(my, t, 16);
            s0 += (float)hs1[(size_t)a * D + j];
        }
    }
    float sum = (s0 + s1) + (s2 + s3);
    float di = dis[i];
    float tt = di * sum + b1[j];
    tt = fmaxf(tt, 0.f);
    float sc = g1[j] * rsqrtf(v1[j] + BNEPS);
    float x1 = (tt - m1[j]) * sc + be1[j];
    float acc = 0.f;
#pragma unroll
    for (int kk = 0; kk < D; kk++) {
        float v = __shfl(x1, kk, 16);
        acc += v * W2s[kk * D + j];
    }
    hs2[(size_t)i * D + j] = (f16)(acc * di);
}

// ---------- layer2 gather + BN2/ReLU ----------
__global__ __launch_bounds__(256) void k_gather2(const unsigned* __restrict__ rowptr,
                                                 const int* __restrict__ srcA,
                                                 const float* __restrict__ dis,
                                                 const f16* __restrict__ hs2,
                                                 const float* __restrict__ b2,
                                                 const float* __restrict__ g2,
                                                 const float* __restrict__ be2,
                                                 const float* __restrict__ m2,
                                                 const float* __restrict__ v2,
                                                 f16* __restrict__ x2) {
    int tid = threadIdx.x;
    int i = blockIdx.x * 16 + (tid >> 4);
    int j = tid & 15;
    unsigned start = rowptr[i], end = rowptr[i + 1];
    float s0 = (float)hs2[(size_t)i * D + j];
    float s1 = 0.f, s2 = 0.f, s3 = 0.f;
    for (unsigned base = start; base < end; base += 16) {
        int idx = (int)base + j;
        int my = (idx < (int)end) ? srcA[idx] : 0;
        int cnt = min(16, (int)(end - base));
        int t = 0;
        for (; t + 4 <= cnt; t += 4) {
            int a = __shfl(my, t, 16);
            int b = __shfl(my, t + 1, 16);
            int c = __shfl(my, t + 2, 16);
            int d = __shfl(my, t + 3, 16);
            s0 += (float)hs2[(size_t)a * D + j];
            s1 += (float)hs2[(size_t)b * D + j];
            s2 += (float)hs2[(size_t)c * D + j];
            s3 += (float)hs2[(size_t)d * D + j];
        }
        for (; t < cnt; t++) {
            int a = __shfl(my, t, 16);
            s0 += (float)hs2[(size_t)a * D + j];
        }
    }
    float sum = (s0 + s1) + (s2 + s3);
    float tt = dis[i] * sum + b2[j];
    tt = fmaxf(tt, 0.f);
    float sc = g2[j] * rsqrtf(v2[j] + BNEPS);
    x2[(size_t)i * D + j] = (f16)((tt - m2[j]) * sc + be2[j]);
}

// ---------- pooling ----------
__global__ __launch_bounds__(256) void k_pool(const f16* __restrict__ x2,
                                              const int* __restrict__ batch,
                                              unsigned* __restrict__ gmaxT,
                                              float* __restrict__ gsum,
                                              unsigned* __restrict__ gcnt) {
    __shared__ unsigned smax[32 * D];
    __shared__ float ssum[32 * D];
    __shared__ unsigned scnt[32];
    int tid = threadIdx.x;
    for (int s = tid; s < 32 * D; s += 256) { smax[s] = 0u; ssum[s] = 0.f; }
    if (tid < 32) scnt[tid] = 0u;
    __syncthreads();
    int n = blockIdx.x * 256 + tid;
    int g0 = batch[blockIdx.x * 256];
    if (n < N) {
        int lg = batch[n] - g0;
        const f16* xp = x2 + (size_t)n * D;
        if (lg < 32) {
            atomicAdd(&scnt[lg], 1u);
#pragma unroll
            for (int j = 0; j < D; j++) {
                float v = (float)xp[j];
                atomicMax(&smax[lg * D + j], f2ord(v));
                atomicAdd(&ssum[lg * D + j], v);
            }
        } else {
            int g = batch[n];
            atomicAdd(&gcnt[g], 1u);
#pragma unroll
            for (int j = 0; j < D; j++) {
                float v = (float)xp[j];
                atomicMax(&gmaxT[(size_t)g * D + j], f2ord(v));
                atomicAdd(&gsum[(size_t)g * D + j], v);
            }
        }
    }
    __syncthreads();
    for (int s = tid; s < 32 * D; s += 256) {
        int slot = s >> 4, j = s & 15;
        if (scnt[slot] > 0u) {
            int g = g0 + slot;
            atomicMax(&gmaxT[(size_t)g * D + j], smax[s]);
            atomicAdd(&gsum[(size_t)g * D + j], ssum[s]);
            if (j == 0) atomicAdd(&gcnt[g], scnt[slot]);
        }
    }
}

// ---------- head ----------
__global__ __launch_bounds__(256) void k_head(const unsigned* __restrict__ gmaxT,
                                              const float* __restrict__ gsum,
                                              const unsigned* __restrict__ gcnt,
                                              const float* __restrict__ Wb,
                                              const float* __restrict__ bb,
                                              const float* __restrict__ Wm,
                                              const float* __restrict__ bm,
                                              float* __restrict__ out) {
    __shared__ float Wbs[32 * 16];
    __shared__ float bbs[16], Wms[16];
    __shared__ float bm0;
    int tid = threadIdx.x;
    for (int i = tid; i < 32 * 16; i += 256) Wbs[i] = Wb[i];
    if (tid < 16) { bbs[tid] = bb[tid]; Wms[tid] = Wm[tid]; }
    if (tid == 0) bm0 = bm[0];
    __syncthreads();
    int g = blockIdx.x * 256 + tid;
    if (g >= G) return;
    float in[32];
    float inv = 1.0f / (float)gcnt[g];
#pragma unroll
    for (int j = 0; j < D; j++) {
        in[j] = ord2f(gmaxT[(size_t)g * D + j]);
        in[16 + j] = gsum[(size_t)g * D + j] * inv;
    }
    float z = bm0;
#pragma unroll
    for (int j = 0; j < 16; j++) {
        float acc = bbs[j];
#pragma unroll
        for (int k = 0; k < 32; k++) acc += in[k] * Wbs[k * 16 + j];
        acc = fmaxf(acc, 0.f);
        z += acc * Wms[j];
    }
    out[g] = 1.0f / (1.0f + expf(-z));
}

extern "C" void kernel_launch(void* const* d_in, const int* in_sizes, int n_in,
                              void* d_out, int out_size, void* d_ws, size_t ws_size,
                              hipStream_t stream) {
    const float* x   = (const float*)d_in[0];
    const int* ei    = (const int*)d_in[1];
    const int* rowp  = ei;
    const int* colp  = ei + E;
    const int* batch = (const int*)d_in[2];
    const float* W1  = (const float*)d_in[3];
    const float* b1  = (const float*)d_in[4];
    const float* g1  = (const float*)d_in[5];
    const float* be1 = (const float*)d_in[6];
    const float* m1  = (const float*)d_in[7];
    const float* v1  = (const float*)d_in[8];
    const float* W2  = (const float*)d_in[9];
    const float* b2  = (const float*)d_in[10];
    const float* g2  = (const float*)d_in[11];
    const float* be2 = (const float*)d_in[12];
    const float* m2  = (const float*)d_in[13];
    const float* v2  = (const float*)d_in[14];
    const float* Wb  = (const float*)d_in[15];
    const float* bb  = (const float*)d_in[16];
    const float* Wm  = (const float*)d_in[17];
    const float* bm  = (const float*)d_in[18];
    float* out = (float*)d_out;

    char* ws = (char*)d_ws;
    // layout (bytes):
    int*      srcA   = (int*)     (ws);                // E i32            [0, 25.6M)
    unsigned* tmp    = (unsigned*)(ws + 25600000);     // E u32 packed     [25.6M, 51.2M)
    f16*      hs1    = (f16*)     (ws + 25600000);     // N*D f16 (6.4MB) — overlays tmp AFTER k_bsort
    f16*      hs2    = (f16*)     (ws + 32000000);     // N*D f16 (6.4MB) — overlays tmp tail
    unsigned* rowptr = (unsigned*)(ws + 51200000);     // (N+1) u32
    float*    dis    = (float*)   (ws + 52000016);     // N f32
    unsigned* bucketCnt  = (unsigned*)(ws + 52800016); // NBKT+1 u32
    unsigned* bucketBase = (unsigned*)(ws + 52801600); // NBKT+1 u32
    unsigned* cursorB    = (unsigned*)(ws + 52803200); // NBKT+1 u32
    unsigned* gmaxT  = (unsigned*)(ws + 52804800);     // G*D u32
    float*    gsum   = (float*)   (ws + 52870336);     // G*D f32
    unsigned* gcnt   = (unsigned*)(ws + 52935872);     // G u32
    f16*      x2buf  = hs1;                            // reuse after gather1

    const int NB = (N + 255) / 256;

    hipMemsetAsync(bucketCnt, 0, (NBKT + 1) * 4, stream);
    hipMemsetAsync(gmaxT, 0, (size_t)G * D * 4, stream);
    hipMemsetAsync(gsum, 0, (size_t)G * D * 4, stream);
    hipMemsetAsync(gcnt, 0, (size_t)G * 4, stream);

    k_hist<<<1024, 256, 0, stream>>>(colp, bucketCnt);
    k_bscan<<<1, 512, 0, stream>>>(bucketCnt, bucketBase, cursorB, rowptr);
    k_bin<<<BINB, 256, 0, stream>>>(rowp, colp, cursorB, tmp);
    k_bsort<<<NBKT, 512, 0, stream>>>(bucketBase, tmp, rowptr, dis, srcA);

    k_gemm1<<<512, 256, 0, stream>>>(x, W1, dis, hs1);

    k_gather1<<<N / 16, 256, 0, stream>>>(rowptr, srcA, dis, hs1,
                                          b1, g1, be1, m1, v1, W2, hs2);
    k_gather2<<<N / 16, 256, 0, stream>>>(rowptr, srcA, dis, hs2,
                                          b2, g2, be2, m2, v2, x2buf);

    k_pool<<<NB, 256, 0, stream>>>(x2buf, batch, gmaxT, gsum, gcnt);
    k_head<<<(G + 255) / 256, 256, 0, stream>>>(gmaxT, gsum, gcnt, Wb, bb, Wm, bm, out);
}

// Round 5
// 552.030 us; speedup vs baseline: 21.2205x; 1.0304x over previous
//
#include <hip/hip_runtime.h>
#include <math.h>

#define N   200000
#define E   6400000
#define IN_ 128
#define D   16
#define G   1024
#define BNEPS 1e-5f

#define BSH   9                      // 512 cols per bucket
#define NBKT  391                    // ceil(N / 512)
#define CH    8192                   // edges per k_bin block
#define BINB  782                    // ceil(E / CH)

typedef _Float16 f16;
typedef __attribute__((ext_vector_type(8))) _Float16 f16x8;
typedef __attribute__((ext_vector_type(4))) float f32x4;

// ---------- helpers ----------
__device__ __forceinline__ unsigned f2ord(float f) {
    unsigned b = __float_as_uint(f);
    return (b & 0x80000000u) ? ~b : (b | 0x80000000u);
}
__device__ __forceinline__ float ord2f(unsigned u) {
    return __uint_as_float((u & 0x80000000u) ? (u & 0x7FFFFFFFu) : ~u);
}

// ---------- bucket histogram ----------
__global__ __launch_bounds__(256) void k_hist(const int* __restrict__ col,
                                              unsigned* __restrict__ bucketCnt) {
    __shared__ unsigned h[NBKT];
    for (int i = threadIdx.x; i < NBKT; i += 256) h[i] = 0u;
    __syncthreads();
    int stride = gridDim.x * 256;
    for (int e = blockIdx.x * 256 + threadIdx.x; e < E; e += stride)
        atomicAdd(&h[col[e] >> BSH], 1u);
    __syncthreads();
    for (int i = threadIdx.x; i < NBKT; i += 256)
        if (h[i]) atomicAdd(&bucketCnt[i], h[i]);
}

// ---------- scan bucket counts ----------
__global__ __launch_bounds__(512) void k_bscan(const unsigned* __restrict__ bucketCnt,
                                               unsigned* __restrict__ bucketBase,
                                               unsigned* __restrict__ cursorB,
                                               unsigned* __restrict__ rowptr) {
    __shared__ unsigned s[512];
    int t = threadIdx.x;
    s[t] = (t < NBKT) ? bucketCnt[t] : 0u;
    __syncthreads();
    for (int off = 1; off < 512; off <<= 1) {
        unsigned v = (t >= off) ? s[t - off] : 0u;
        __syncthreads();
        s[t] += v;
        __syncthreads();
    }
    unsigned excl = (t > 0) ? s[t - 1] : 0u;
    if (t <= NBKT) {
        bucketBase[t] = excl;
        cursorB[t] = excl;
    }
    if (t == 0) rowptr[N] = E;
}

// ---------- phase 1: bin edges by bucket (512 thr, no sbkt, bucket-major copyout) ----------
__global__ __launch_bounds__(512) void k_bin(const int* __restrict__ row,
                                             const int* __restrict__ col,
                                             unsigned* __restrict__ cursorB,
                                             unsigned* __restrict__ tmp) {
    __shared__ unsigned hist[512];   // after scan phase: lbase
    __shared__ unsigned offs[512];   // inclusive scan (lbase[b+1])
    __shared__ unsigned lcur[512];
    __shared__ unsigned gbase[512];
    __shared__ unsigned sbuf[CH];    // 32 KB
    int tid = threadIdx.x;
    int base = blockIdx.x * CH;
    int cnt = min(CH, E - base);
    hist[tid] = 0u;
    __syncthreads();
    for (int i = tid; i < cnt; i += 512)
        atomicAdd(&hist[col[base + i] >> BSH], 1u);
    __syncthreads();
    offs[tid] = hist[tid];
    __syncthreads();
    for (int off = 1; off < 512; off <<= 1) {
        unsigned v = (tid >= off) ? offs[tid - off] : 0u;
        __syncthreads();
        offs[tid] += v;
        __syncthreads();
    }
    unsigned lb = (tid > 0) ? offs[tid - 1] : 0u;
    unsigned c0 = offs[tid] - lb;
    lcur[tid] = lb;
    hist[tid] = lb;   // hist now holds lbase
    if (tid < NBKT && c0) gbase[tid] = atomicAdd(&cursorB[tid], c0);
    __syncthreads();
    for (int i = tid; i < cnt; i += 512) {
        int c = col[base + i];
        int r = row[base + i];
        int b = c >> BSH;
        unsigned p = atomicAdd(&lcur[b], 1u);
        sbuf[p] = (unsigned)r | ((unsigned)(c & ((1 << BSH) - 1)) << 18);
    }
    __syncthreads();
    // bucket-major coalesced copy-out: one wave per bucket
    int wv = tid >> 6, ln = tid & 63;
    for (int b = wv; b < NBKT; b += 8) {
        unsigned l0 = hist[b], l1 = offs[b], gb = gbase[b];
        for (unsigned i2 = l0 + ln; i2 < l1; i2 += 64)
            tmp[gb + (i2 - l0)] = sbuf[i2];
    }
}

// ---------- phase 2: per-bucket counting sort ----------
__global__ __launch_bounds__(512) void k_bsort(const unsigned* __restrict__ bucketBase,
                                               const unsigned* __restrict__ tmp,
                                               unsigned* __restrict__ rowptr,
                                               float* __restrict__ dis,
                                               int* __restrict__ srcA) {
    __shared__ unsigned cnt[512];
    __shared__ unsigned offs[512];
    __shared__ unsigned lcur[512];
    int tid = threadIdx.x;
    int b = blockIdx.x;
    unsigned s0 = bucketBase[b], s1 = bucketBase[b + 1];
    cnt[tid] = 0u;
    __syncthreads();
    for (unsigned i = s0 + tid; i < s1; i += 512)
        atomicAdd(&cnt[tmp[i] >> 18], 1u);
    __syncthreads();
    offs[tid] = cnt[tid];
    __syncthreads();
    for (int off = 1; off < 512; off <<= 1) {
        unsigned v = (tid >= off) ? offs[tid - off] : 0u;
        __syncthreads();
        offs[tid] += v;
        __syncthreads();
    }
    unsigned excl = (tid > 0) ? offs[tid - 1] : 0u;
    int c = (b << BSH) + tid;
    if (c < N) {
        rowptr[c] = s0 + excl;
        dis[c] = rsqrtf((float)cnt[tid] + 1.0f);
    }
    lcur[tid] = s0 + excl;
    __syncthreads();
    for (unsigned i = s0 + tid; i < s1; i += 512) {
        unsigned p = tmp[i];
        unsigned pos = atomicAdd(&lcur[p >> 18], 1u);
        srcA[pos] = (int)(p & 0x3FFFFu);
    }
}

// ---------- hs1 = f16((x @ W1) * dis) via MFMA 16x16x32 f16 ----------
__global__ __launch_bounds__(256) void k_gemm1(const float* __restrict__ x,
                                               const float* __restrict__ W1,
                                               const float* __restrict__ dis,
                                               f16* __restrict__ hs) {
    __shared__ f16 Wh[IN_ * D];
    int tid = threadIdx.x;
    for (int i = tid; i < IN_ * D; i += 256) Wh[i] = (f16)W1[i];
    __syncthreads();
    int lane = tid & 63;
    int wave = tid >> 6;
    int m = lane & 15, quad = lane >> 4;
    f16x8 bfrag[4];
#pragma unroll
    for (int s = 0; s < 4; s++)
#pragma unroll
        for (int jj = 0; jj < 8; jj++)
            bfrag[s][jj] = Wh[(s * 32 + quad * 8 + jj) * D + m];
    int gwave = blockIdx.x * 4 + wave;
    int nwaves = gridDim.x * 4;
    const int ntiles = N / 16;
    for (int t = gwave; t < ntiles; t += nwaves) {
        int n0 = t * 16;
        const float* xrow = x + (size_t)(n0 + m) * IN_ + quad * 8;
        f32x4 acc = {0.f, 0.f, 0.f, 0.f};
#pragma unroll
        for (int s = 0; s < 4; s++) {
            float4 lo = *(const float4*)(xrow + s * 32);
            float4 hi = *(const float4*)(xrow + s * 32 + 4);
            f16x8 a;
            a[0] = (f16)lo.x; a[1] = (f16)lo.y; a[2] = (f16)lo.z; a[3] = (f16)lo.w;
            a[4] = (f16)hi.x; a[5] = (f16)hi.y; a[6] = (f16)hi.z; a[7] = (f16)hi.w;
            acc = __builtin_amdgcn_mfma_f32_16x16x32_f16(a, bfrag[s], acc, 0, 0, 0);
        }
#pragma unroll
        for (int r = 0; r < 4; r++) {
            int rowi = n0 + quad * 4 + r;
            hs[(size_t)rowi * D + m] = (f16)(acc[r] * dis[rowi]);
        }
    }
}

// ---------- wide gather core: sums 16 features of CSR segment into per-lane scalar ----------
// 16 lanes per node: lane j -> feature j. Returns the segment sum (excl. nothing; seed passed in).
__device__ __forceinline__ float gather_row_sum(const unsigned* __restrict__ rowptr,
                                                const int* __restrict__ srcA,
                                                const f16* __restrict__ hs,
                                                int i, int j, float seed) {
    unsigned start = rowptr[i], end = rowptr[i + 1];
    unsigned len = end - start;
    unsigned nfull = len & ~7u;
    int es = j >> 1;          // edge slot 0..7
    int half = j & 1;         // which 8-feature half
    float acc[8] = {0.f, 0.f, 0.f, 0.f, 0.f, 0.f, 0.f, 0.f};
    for (unsigned off = 0; off < nfull; off += 8) {
        int idx = srcA[start + off + (j & 7)];
        int src = __shfl(idx, es, 16);
        const f16x8 v = *(const f16x8*)(hs + ((size_t)src << 4) + (half << 3));
#pragma unroll
        for (int k = 0; k < 8; k++) acc[k] += (float)v[k];
    }
    // butterfly over edge-slot bits (keep half fixed)
#pragma unroll
    for (int mask = 2; mask <= 8; mask <<= 1) {
#pragma unroll
        for (int k = 0; k < 8; k++) acc[k] += __shfl_xor(acc[k], mask, 16);
    }
    // redistribute: lane j wants acc[j&7] from lane (j>>3) (lane0=half0, lane1=half1)
    float x = 0.f;
    int srcl = j >> 3;
#pragma unroll
    for (int k = 0; k < 8; k++) {
        float vk = __shfl(acc[k], srcl, 16);
        if ((j & 7) == k) x = vk;
    }
    // tail (<8 edges) scalar path
    float xt = seed;
    for (unsigned e = start + nfull; e < end; e++) {
        int src = srcA[e];
        xt += (float)hs[((size_t)src << 4) + j];
    }
    return x + xt;
}

// ---------- layer1 gather + BN1/ReLU + GEMM2 ----------
__global__ __launch_bounds__(256) void k_gather1(const unsigned* __restrict__ rowptr,
                                                 const int* __restrict__ srcA,
                                                 const float* __restrict__ dis,
                                                 const f16* __restrict__ hs1,
                                                 const float* __restrict__ b1,
                                                 const float* __restrict__ g1,
                                                 const float* __restrict__ be1,
                                                 const float* __restrict__ m1,
                                                 const float* __restrict__ v1,
                                                 const float* __restrict__ W2,
                                                 f16* __restrict__ hs2) {
    __shared__ float W2s[D * D];
    int tid = threadIdx.x;
    if (tid < D * D) W2s[tid] = W2[tid];
    __syncthreads();
    int i = blockIdx.x * 16 + (tid >> 4);
    int j = tid & 15;
    float self = (float)hs1[((size_t)i << 4) + j];
    float sum = gather_row_sum(rowptr, srcA, hs1, i, j, self);
    float di = dis[i];
    float tt = di * sum + b1[j];
    tt = fmaxf(tt, 0.f);
    float sc = g1[j] * rsqrtf(v1[j] + BNEPS);
    float x1 = (tt - m1[j]) * sc + be1[j];
    float acc = 0.f;
#pragma unroll
    for (int kk = 0; kk < D; kk++) {
        float v = __shfl(x1, kk, 16);
        acc += v * W2s[kk * D + j];
    }
    hs2[((size_t)i << 4) + j] = (f16)(acc * di);
}

// ---------- layer2 gather + BN2/ReLU ----------
__global__ __launch_bounds__(256) void k_gather2(const unsigned* __restrict__ rowptr,
                                                 const int* __restrict__ srcA,
                                                 const float* __restrict__ dis,
                                                 const f16* __restrict__ hs2,
                                                 const float* __restrict__ b2,
                                                 const float* __restrict__ g2,
                                                 const float* __restrict__ be2,
                                                 const float* __restrict__ m2,
                                                 const float* __restrict__ v2,
                                                 f16* __restrict__ x2) {
    int tid = threadIdx.x;
    int i = blockIdx.x * 16 + (tid >> 4);
    int j = tid & 15;
    float self = (float)hs2[((size_t)i << 4) + j];
    float sum = gather_row_sum(rowptr, srcA, hs2, i, j, self);
    float tt = dis[i] * sum + b2[j];
    tt = fmaxf(tt, 0.f);
    float sc = g2[j] * rsqrtf(v2[j] + BNEPS);
    x2[((size_t)i << 4) + j] = (f16)((tt - m2[j]) * sc + be2[j]);
}

// ---------- pooling ----------
__global__ __launch_bounds__(256) void k_pool(const f16* __restrict__ x2,
                                              const int* __restrict__ batch,
                                              unsigned* __restrict__ gmaxT,
                                              float* __restrict__ gsum,
                                              unsigned* __restrict__ gcnt) {
    __shared__ unsigned smax[32 * D];
    __shared__ float ssum[32 * D];
    __shared__ unsigned scnt[32];
    int tid = threadIdx.x;
    for (int s = tid; s < 32 * D; s += 256) { smax[s] = 0u; ssum[s] = 0.f; }
    if (tid < 32) scnt[tid] = 0u;
    __syncthreads();
    int n = blockIdx.x * 256 + tid;
    int g0 = batch[blockIdx.x * 256];
    if (n < N) {
        int lg = batch[n] - g0;
        const f16* xp = x2 + (size_t)n * D;
        if (lg < 32) {
            atomicAdd(&scnt[lg], 1u);
#pragma unroll
            for (int j = 0; j < D; j++) {
                float v = (float)xp[j];
                atomicMax(&smax[lg * D + j], f2ord(v));
                atomicAdd(&ssum[lg * D + j], v);
            }
        } else {
            int g = batch[n];
            atomicAdd(&gcnt[g], 1u);
#pragma unroll
            for (int j = 0; j < D; j++) {
                float v = (float)xp[j];
                atomicMax(&gmaxT[(size_t)g * D + j], f2ord(v));
                atomicAdd(&gsum[(size_t)g * D + j], v);
            }
        }
    }
    __syncthreads();
    for (int s = tid; s < 32 * D; s += 256) {
        int slot = s >> 4, j = s & 15;
        if (scnt[slot] > 0u) {
            int g = g0 + slot;
            atomicMax(&gmaxT[(size_t)g * D + j], smax[s]);
            atomicAdd(&gsum[(size_t)g * D + j], ssum[s]);
            if (j == 0) atomicAdd(&gcnt[g], scnt[slot]);
        }
    }
}

// ---------- head ----------
__global__ __launch_bounds__(256) void k_head(const unsigned* __restrict__ gmaxT,
                                              const float* __restrict__ gsum,
                                              const unsigned* __restrict__ gcnt,
                                              const float* __restrict__ Wb,
                                              const float* __restrict__ bb,
                                              const float* __restrict__ Wm,
                                              const float* __restrict__ bm,
                                              float* __restrict__ out) {
    __shared__ float Wbs[32 * 16];
    __shared__ float bbs[16], Wms[16];
    __shared__ float bm0;
    int tid = threadIdx.x;
    for (int i = tid; i < 32 * 16; i += 256) Wbs[i] = Wb[i];
    if (tid < 16) { bbs[tid] = bb[tid]; Wms[tid] = Wm[tid]; }
    if (tid == 0) bm0 = bm[0];
    __syncthreads();
    int g = blockIdx.x * 256 + tid;
    if (g >= G) return;
    float in[32];
    float inv = 1.0f / (float)gcnt[g];
#pragma unroll
    for (int j = 0; j < D; j++) {
        in[j] = ord2f(gmaxT[(size_t)g * D + j]);
        in[16 + j] = gsum[(size_t)g * D + j] * inv;
    }
    float z = bm0;
#pragma unroll
    for (int j = 0; j < 16; j++) {
        float acc = bbs[j];
#pragma unroll
        for (int k = 0; k < 32; k++) acc += in[k] * Wbs[k * 16 + j];
        acc = fmaxf(acc, 0.f);
        z += acc * Wms[j];
    }
    out[g] = 1.0f / (1.0f + expf(-z));
}

extern "C" void kernel_launch(void* const* d_in, const int* in_sizes, int n_in,
                              void* d_out, int out_size, void* d_ws, size_t ws_size,
                              hipStream_t stream) {
    const float* x   = (const float*)d_in[0];
    const int* ei    = (const int*)d_in[1];
    const int* rowp  = ei;
    const int* colp  = ei + E;
    const int* batch = (const int*)d_in[2];
    const float* W1  = (const float*)d_in[3];
    const float* b1  = (const float*)d_in[4];
    const float* g1  = (const float*)d_in[5];
    const float* be1 = (const float*)d_in[6];
    const float* m1  = (const float*)d_in[7];
    const float* v1  = (const float*)d_in[8];
    const float* W2  = (const float*)d_in[9];
    const float* b2  = (const float*)d_in[10];
    const float* g2  = (const float*)d_in[11];
    const float* be2 = (const float*)d_in[12];
    const float* m2  = (const float*)d_in[13];
    const float* v2  = (const float*)d_in[14];
    const float* Wb  = (const float*)d_in[15];
    const float* bb  = (const float*)d_in[16];
    const float* Wm  = (const float*)d_in[17];
    const float* bm  = (const float*)d_in[18];
    float* out = (float*)d_out;

    char* ws = (char*)d_ws;
    int*      srcA   = (int*)     (ws);                // E i32            [0, 25.6M)
    unsigned* tmp    = (unsigned*)(ws + 25600000);     // E u32 packed     [25.6M, 51.2M)
    f16*      hs1    = (f16*)     (ws + 25600000);     // N*D f16 (6.4MB) — overlays tmp AFTER k_bsort
    f16*      hs2    = (f16*)     (ws + 32000000);     // N*D f16 (6.4MB)
    unsigned* rowptr = (unsigned*)(ws + 51200000);     // (N+1) u32
    float*    dis    = (float*)   (ws + 52000016);     // N f32
    unsigned* bucketCnt  = (unsigned*)(ws + 52800016);
    unsigned* bucketBase = (unsigned*)(ws + 52801600);
    unsigned* cursorB    = (unsigned*)(ws + 52803200);
    unsigned* gmaxT  = (unsigned*)(ws + 52804800);
    float*    gsum   = (float*)   (ws + 52870336);
    unsigned* gcnt   = (unsigned*)(ws + 52935872);
    f16*      x2buf  = hs1;

    const int NB = (N + 255) / 256;

    hipMemsetAsync(bucketCnt, 0, (NBKT + 1) * 4, stream);
    hipMemsetAsync(gmaxT, 0, (size_t)G * D * 4, stream);
    hipMemsetAsync(gsum, 0, (size_t)G * D * 4, stream);
    hipMemsetAsync(gcnt, 0, (size_t)G * 4, stream);

    k_hist<<<1024, 256, 0, stream>>>(colp, bucketCnt);
    k_bscan<<<1, 512, 0, stream>>>(bucketCnt, bucketBase, cursorB, rowptr);
    k_bin<<<BINB, 512, 0, stream>>>(rowp, colp, cursorB, tmp);
    k_bsort<<<NBKT, 512, 0, stream>>>(bucketBase, tmp, rowptr, dis, srcA);

    k_gemm1<<<512, 256, 0, stream>>>(x, W1, dis, hs1);

    k_gather1<<<N / 16, 256, 0, stream>>>(rowptr, srcA, dis, hs1,
                                          b1, g1, be1, m1, v1, W2, hs2);
    k_gather2<<<N / 16, 256, 0, stream>>>(rowptr, srcA, dis, hs2,
                                          b2, g2, be2, m2, v2, x2buf);

    k_pool<<<NB, 256, 0, stream>>>(x2buf, batch, gmaxT, gsum, gcnt);
    k_head<<<(G + 255) / 256, 256, 0, stream>>>(gmaxT, gsum, gcnt, Wb, bb, Wm, bm, out);
}